// Round 7
// baseline (310.946 us; speedup 1.0000x reference)
//
#include <hip/hip_runtime.h>
#include <stdint.h>
#include <stddef.h>

#define DIM 1024
#define EPS 1e-8f

typedef __attribute__((ext_vector_type(4))) float f32x4;
typedef __attribute__((ext_vector_type(2))) long longx2;   // 16 B = 2 fp8 k-halves

// async global->LDS, 16B per lane, wave-uniform LDS base + lane*16
__device__ __forceinline__ void async_copy16(const void* g, void* l) {
    __builtin_amdgcn_global_load_lds(
        (__attribute__((address_space(1))) void*)const_cast<void*>(g),
        (__attribute__((address_space(3))) void*)(l), 16, 0, 0);
}

// drain all but newest N vmem ops, then barrier
#define PIPE_SYNC(N) asm volatile("s_waitcnt vmcnt(" #N ")\n\ts_barrier" ::: "memory")
#define LGK0() asm volatile("s_waitcnt lgkmcnt(0)" ::: "memory")

// ---------------------------------------------------------------------------
// Prep: wave-per-row. Unit-normalize, scale by 16 (undone in epilogue), cast
// to OCP fp8 e4m3. Rows stored PERMUTED per 64-B k-window: 16-B chunk q
// holds bytes [q*8,+8) and [32+q*8,+8) of the window so the GEMM fetches
// both k-steps of a quad-fragment with ONE ds_read_b128 (R6-verified zero
// bank conflicts). x-rows also emit exact fp32 positive sim, zero
// rowsum[row]; row 0 zeroes the done-counter for the gemm's fused loss tail.
// ---------------------------------------------------------------------------
__global__ __launch_bounds__(256)
void prep_all(const float* __restrict__ x, const float* __restrict__ pos,
              const float* __restrict__ neg,
              unsigned char* __restrict__ Xn, unsigned char* __restrict__ Nn,
              float* __restrict__ simOut, float* __restrict__ rowsum,
              int* __restrict__ done, int bn) {
    const int lane = threadIdx.x & 63;
    const int wave = threadIdx.x >> 6;
    const int grow = blockIdx.x * 4 + wave;
    const bool isX = grow < bn;
    const int row  = isX ? grow : grow - bn;
    const float* src = isX ? x : neg;
    unsigned char* dst = isX ? Xn : Nn;

    const float4* s = (const float4*)(src + (size_t)row * DIM);
    float4 xv[4], pv[4];
    float sxx = 0.f, spp = 0.f, sxp = 0.f;
#pragma unroll
    for (int i = 0; i < 4; i++) {
        xv[i] = s[lane + 64 * i];
        sxx += xv[i].x * xv[i].x + xv[i].y * xv[i].y + xv[i].z * xv[i].z + xv[i].w * xv[i].w;
    }
    if (isX) {
        const float4* p = (const float4*)(pos + (size_t)row * DIM);
#pragma unroll
        for (int i = 0; i < 4; i++) {
            pv[i] = p[lane + 64 * i];
            spp += pv[i].x * pv[i].x + pv[i].y * pv[i].y + pv[i].z * pv[i].z + pv[i].w * pv[i].w;
            sxp += xv[i].x * pv[i].x + xv[i].y * pv[i].y + xv[i].z * pv[i].z + xv[i].w * pv[i].w;
        }
#pragma unroll
        for (int off = 1; off < 64; off <<= 1) {
            sxx += __shfl_xor(sxx, off);
            spp += __shfl_xor(spp, off);
            sxp += __shfl_xor(sxp, off);
        }
    } else {
#pragma unroll
        for (int off = 1; off < 64; off <<= 1) sxx += __shfl_xor(sxx, off);
    }
    const float nx  = sqrtf(sxx);
    const float inv = (nx > 0.f) ? (16.f / nx) : 0.f;   // x16 -> e4m3 sweet spot
    if (isX && lane == 0) {
        const float np = sqrtf(spp);
        simOut[row] = sxp / fmaxf(nx * np, EPS);
        rowsum[row] = 0.f;
        if (row == 0) *done = 0;
    }
    unsigned int t;
    t = __builtin_amdgcn_cvt_pk_fp8_f32(xv[0].x * inv, xv[0].y * inv, 0, false);
    unsigned int q0 = __builtin_amdgcn_cvt_pk_fp8_f32(xv[0].z * inv, xv[0].w * inv, t, true);
    t = __builtin_amdgcn_cvt_pk_fp8_f32(xv[1].x * inv, xv[1].y * inv, 0, false);
    unsigned int q1 = __builtin_amdgcn_cvt_pk_fp8_f32(xv[1].z * inv, xv[1].w * inv, t, true);
    t = __builtin_amdgcn_cvt_pk_fp8_f32(xv[2].x * inv, xv[2].y * inv, 0, false);
    unsigned int q2 = __builtin_amdgcn_cvt_pk_fp8_f32(xv[2].z * inv, xv[2].w * inv, t, true);
    t = __builtin_amdgcn_cvt_pk_fp8_f32(xv[3].x * inv, xv[3].y * inv, 0, false);
    unsigned int q3 = __builtin_amdgcn_cvt_pk_fp8_f32(xv[3].z * inv, xv[3].w * inv, t, true);

    const int m  = lane & 3;
    const int d0 = (m & 1) * 32 + (m >> 1) * 8;          // 0,32,8,40
    unsigned char* wbase = dst + (size_t)row * DIM + (lane >> 2) * 64;
    *(unsigned long long*)(wbase + d0)      = ((unsigned long long)q1 << 32) | q0;
    *(unsigned long long*)(wbase + d0 + 16) = ((unsigned long long)q3 << 32) | q2;
}

// ---------------------------------------------------------------------------
// Fused fp8 GEMM + loss tail: rowsum[i] += sum_j exp(dot/256); last block
// (device-scope done-counter) computes loss = mean(log(rowsum)-sim).
// 128x128 tile, BK=64 B permuted windows, TWO-stage LDS (exactly 32 KB ->
// 5 blocks/CU), prefetch distance 2 phases via s_waitcnt vmcnt(4)+s_barrier.
// WAR on the 2-buffer scheme: lgkmcnt(0) after fragment loads, THEN restage
// the same buffer for phase s+2. Per phase: 8 ds_read_b128 + 32 MFMA.
// ---------------------------------------------------------------------------
__global__ __launch_bounds__(256)
void gemm_exp_rowsum(const unsigned char* __restrict__ Xn,
                     const unsigned char* __restrict__ Nn,
                     float* __restrict__ rowsum,
                     const float* __restrict__ sim, float* __restrict__ out,
                     int* __restrict__ done, int bn) {
    constexpr int KB   = DIM;        // 1024 bytes per fp8 row
    constexpr int BK   = 64;         // bytes per stage-row (one permuted window)
    constexpr int BUFB = 128 * BK;   // 8 KB per buffer
    __shared__ __align__(16) unsigned char Ash[2][BUFB];
    __shared__ __align__(16) unsigned char Bsh[2][BUFB];   // total exactly 32 KB

    const int tid  = threadIdx.x;
    const int lane = tid & 63;
    const int wave = tid >> 6;
    const int rowBase = blockIdx.y * 128;
    const int colBase = blockIdx.x * 128;

    // staging: one glds = 1 KB = 16 rows x 64 B; lane -> (row, chunk)
    const int srow   = lane >> 2;                       // 0..15
    const int schunk = (lane & 3) ^ ((srow >> 1) & 3);  // global-side swizzle
    const unsigned char* gA = Xn + (size_t)(rowBase + wave * 16 + srow) * KB + schunk * 16;
    const unsigned char* gB = Nn + (size_t)(colBase + wave * 16 + srow) * KB + schunk * 16;
    const int lgrp0 = (wave * 16) * BK;
    const int lgrp1 = (wave * 16 + 64) * BK;

    const f32x4 fz = {0.f, 0.f, 0.f, 0.f};
    f32x4 acc[4][4];
#pragma unroll
    for (int mi = 0; mi < 4; mi++)
#pragma unroll
        for (int ni = 0; ni < 4; ni++) acc[mi][ni] = fz;

    const int m0   = (wave >> 1) * 64;
    const int n0   = (wave & 1) * 64;
    const int quad = lane >> 4;
    const int mrow = lane & 15;
    const int kx   = (mrow >> 1) & 3;    // read-side swizzle key

    int aoff[4], boff[4];
#pragma unroll
    for (int i = 0; i < 4; i++) {
        aoff[i] = (m0 + i * 16 + mrow) * BK + ((quad ^ kx) << 4);
        boff[i] = (n0 + i * 16 + mrow) * BK + ((quad ^ kx) << 4);
    }

#define STAGE(buf, stg)                                                  \
    do {                                                                 \
        const int kq = (stg) * BK;                                       \
        async_copy16(gA + kq,            &Ash[buf][lgrp0]);              \
        async_copy16(gA + 64 * KB + kq,  &Ash[buf][lgrp1]);              \
        async_copy16(gB + kq,            &Bsh[buf][lgrp0]);              \
        async_copy16(gB + 64 * KB + kq,  &Bsh[buf][lgrp1]);              \
    } while (0)

// one phase: fragment loads from buf, lgkmcnt(0) (WAR gate), optional
// restage of the SAME buf for phase s+2, then 32 MFMAs.
#define PHASE(buf, STMT)                                                 \
    do {                                                                 \
        longx2 a2[4], b2[4];                                             \
        _Pragma("unroll")                                                \
        for (int i = 0; i < 4; i++) {                                    \
            a2[i] = *(const longx2*)&Ash[buf][aoff[i]];                  \
            b2[i] = *(const longx2*)&Bsh[buf][boff[i]];                  \
        }                                                                \
        LGK0();                                                          \
        STMT;                                                            \
        _Pragma("unroll")                                                \
        for (int mi = 0; mi < 4; mi++)                                   \
            _Pragma("unroll")                                            \
            for (int ni = 0; ni < 4; ni++) {                             \
                acc[mi][ni] = __builtin_amdgcn_mfma_f32_16x16x32_fp8_fp8( \
                    a2[mi].x, b2[ni].x, acc[mi][ni], 0, 0, 0);           \
                acc[mi][ni] = __builtin_amdgcn_mfma_f32_16x16x32_fp8_fp8( \
                    a2[mi].y, b2[ni].y, acc[mi][ni], 0, 0, 0);           \
            }                                                            \
    } while (0)

    STAGE(0, 0);
    STAGE(1, 1);
    // 16 phases; phase s reads buf s&1; restages same buf with window s+2
    for (int it = 0; it < 7; it++) {
        const int s = 2 * it;
        PIPE_SYNC(4); PHASE(0, STAGE(0, s + 2));
        PIPE_SYNC(4); PHASE(1, STAGE(1, s + 3));
    }
    PIPE_SYNC(4); PHASE(0, (void)0);   // phase 14
    PIPE_SYNC(0); PHASE(1, (void)0);   // phase 15
#undef STAGE
#undef PHASE

    // epilogue: undo x16*x16 scaling (1/256), exp, 16-col reduce, atomics.
    // C/D layout: col=lane&15, row=quad*4+reg.
#pragma unroll
    for (int mi = 0; mi < 4; mi++) {
        float rs0 = 0.f, rs1 = 0.f, rs2 = 0.f, rs3 = 0.f;
#pragma unroll
        for (int ni = 0; ni < 4; ni++) {
            rs0 += __expf(acc[mi][ni].x * 0.00390625f);
            rs1 += __expf(acc[mi][ni].y * 0.00390625f);
            rs2 += __expf(acc[mi][ni].z * 0.00390625f);
            rs3 += __expf(acc[mi][ni].w * 0.00390625f);
        }
#pragma unroll
        for (int off = 1; off < 16; off <<= 1) {
            rs0 += __shfl_xor(rs0, off);
            rs1 += __shfl_xor(rs1, off);
            rs2 += __shfl_xor(rs2, off);
            rs3 += __shfl_xor(rs3, off);
        }
        if ((lane & 15) == 0) {
            const int r = rowBase + m0 + mi * 16 + quad * 4;
            atomicAdd(&rowsum[r + 0], rs0);
            atomicAdd(&rowsum[r + 1], rs1);
            atomicAdd(&rowsum[r + 2], rs2);
            atomicAdd(&rowsum[r + 3], rs3);
        }
    }

    // ---- fused loss tail: last finished block reduces log(rowsum)-sim ----
    // LDS is dead now; overlay the flag/reduction scratch to stay at 32 KB.
    int*   sflag = (int*)&Ash[0][0];
    float* sred  = (float*)&Ash[0][64];
    __syncthreads();            // all waves' rowsum atomics drained (vmcnt)
    __threadfence();            // visible device-wide before ticket
    if (tid == 0) *sflag = atomicAdd(done, 1);
    __syncthreads();
    if (*sflag == (int)(gridDim.x * gridDim.y) - 1) {
        float acc2 = 0.f;
        for (int i = tid; i < bn; i += 256)
            acc2 += __logf(atomicAdd(&rowsum[i], 0.f)) - sim[i];  // coherent read
#pragma unroll
        for (int off = 1; off < 64; off <<= 1) acc2 += __shfl_xor(acc2, off);
        if (lane == 0) sred[wave] = acc2;
        __syncthreads();
        if (tid == 0)
            out[0] = (sred[0] + sred[1] + sred[2] + sred[3]) / (float)bn;
    }
}

extern "C" void kernel_launch(void* const* d_in, const int* in_sizes, int n_in,
                              void* d_out, int out_size, void* d_ws, size_t ws_size,
                              hipStream_t stream) {
    const float* x   = (const float*)d_in[0];
    const float* pos = (const float*)d_in[1];
    const float* neg = (const float*)d_in[2];
    const int bn = in_sizes[0] / DIM;  // 4096
    const int cn = in_sizes[2] / DIM;  // 8192

    // ws: Xn fp8 [bn*DIM] | Nn fp8 [cn*DIM] | sim f32 [bn] | rowsum f32 [bn] | done
    unsigned char* Xn = (unsigned char*)d_ws;
    unsigned char* Nn = Xn + (size_t)bn * DIM;
    float* sim    = (float*)(Nn + (size_t)cn * DIM);
    float* rowsum = sim + bn;
    int*   done   = (int*)(rowsum + bn);

    prep_all<<<dim3((bn + cn) / 4), dim3(256), 0, stream>>>(
        x, pos, neg, Xn, Nn, sim, rowsum, done, bn);
    gemm_exp_rowsum<<<dim3(cn / 128, bn / 128), dim3(256), 0, stream>>>(
        Xn, Nn, rowsum, sim, (float*)d_out, done, bn);
}

// Round 8
// 176.753 us; speedup vs baseline: 1.7592x; 1.7592x over previous
//
#include <hip/hip_runtime.h>
#include <stdint.h>
#include <stddef.h>

#define DIM 1024
#define EPS 1e-8f

typedef __attribute__((ext_vector_type(4))) float f32x4;
typedef __attribute__((ext_vector_type(2))) long longx2;   // 16 B = 2 fp8 k-halves

// async global->LDS, 16B per lane, wave-uniform LDS base + lane*16
__device__ __forceinline__ void async_copy16(const void* g, void* l) {
    __builtin_amdgcn_global_load_lds(
        (__attribute__((address_space(1))) void*)const_cast<void*>(g),
        (__attribute__((address_space(3))) void*)(l), 16, 0, 0);
}

// ---------------------------------------------------------------------------
// Prep: wave-per-row. Unit-normalize, scale by 16 (undone in epilogue), cast
// to OCP fp8 e4m3. Rows stored PERMUTED per 64-B k-window: 16-B chunk q
// holds bytes [q*8,+8) and [32+q*8,+8) of the window so the GEMM fetches
// both k-steps of a quad-fragment with ONE ds_read_b128 (R6-verified zero
// bank conflicts). x-rows also emit exact fp32 positive sim + zero rowsum.
// ---------------------------------------------------------------------------
__global__ __launch_bounds__(256)
void prep_all(const float* __restrict__ x, const float* __restrict__ pos,
              const float* __restrict__ neg,
              unsigned char* __restrict__ Xn, unsigned char* __restrict__ Nn,
              float* __restrict__ simOut, float* __restrict__ rowsum, int bn) {
    const int lane = threadIdx.x & 63;
    const int wave = threadIdx.x >> 6;
    const int grow = blockIdx.x * 4 + wave;
    const bool isX = grow < bn;
    const int row  = isX ? grow : grow - bn;
    const float* src = isX ? x : neg;
    unsigned char* dst = isX ? Xn : Nn;

    const float4* s = (const float4*)(src + (size_t)row * DIM);
    float4 xv[4], pv[4];
    float sxx = 0.f, spp = 0.f, sxp = 0.f;
#pragma unroll
    for (int i = 0; i < 4; i++) {
        xv[i] = s[lane + 64 * i];
        sxx += xv[i].x * xv[i].x + xv[i].y * xv[i].y + xv[i].z * xv[i].z + xv[i].w * xv[i].w;
    }
    if (isX) {
        const float4* p = (const float4*)(pos + (size_t)row * DIM);
#pragma unroll
        for (int i = 0; i < 4; i++) {
            pv[i] = p[lane + 64 * i];
            spp += pv[i].x * pv[i].x + pv[i].y * pv[i].y + pv[i].z * pv[i].z + pv[i].w * pv[i].w;
            sxp += xv[i].x * pv[i].x + xv[i].y * pv[i].y + xv[i].z * pv[i].z + xv[i].w * pv[i].w;
        }
#pragma unroll
        for (int off = 1; off < 64; off <<= 1) {
            sxx += __shfl_xor(sxx, off);
            spp += __shfl_xor(spp, off);
            sxp += __shfl_xor(sxp, off);
        }
    } else {
#pragma unroll
        for (int off = 1; off < 64; off <<= 1) sxx += __shfl_xor(sxx, off);
    }
    const float nx  = sqrtf(sxx);
    const float inv = (nx > 0.f) ? (16.f / nx) : 0.f;   // x16 -> e4m3 sweet spot
    if (isX && lane == 0) {
        const float np = sqrtf(spp);
        simOut[row] = sxp / fmaxf(nx * np, EPS);
        rowsum[row] = 0.f;
    }
    unsigned int t;
    t = __builtin_amdgcn_cvt_pk_fp8_f32(xv[0].x * inv, xv[0].y * inv, 0, false);
    unsigned int q0 = __builtin_amdgcn_cvt_pk_fp8_f32(xv[0].z * inv, xv[0].w * inv, t, true);
    t = __builtin_amdgcn_cvt_pk_fp8_f32(xv[1].x * inv, xv[1].y * inv, 0, false);
    unsigned int q1 = __builtin_amdgcn_cvt_pk_fp8_f32(xv[1].z * inv, xv[1].w * inv, t, true);
    t = __builtin_amdgcn_cvt_pk_fp8_f32(xv[2].x * inv, xv[2].y * inv, 0, false);
    unsigned int q2 = __builtin_amdgcn_cvt_pk_fp8_f32(xv[2].z * inv, xv[2].w * inv, t, true);
    t = __builtin_amdgcn_cvt_pk_fp8_f32(xv[3].x * inv, xv[3].y * inv, 0, false);
    unsigned int q3 = __builtin_amdgcn_cvt_pk_fp8_f32(xv[3].z * inv, xv[3].w * inv, t, true);

    const int m  = lane & 3;
    const int d0 = (m & 1) * 32 + (m >> 1) * 8;          // 0,32,8,40
    unsigned char* wbase = dst + (size_t)row * DIM + (lane >> 2) * 64;
    *(unsigned long long*)(wbase + d0)      = ((unsigned long long)q1 << 32) | q0;
    *(unsigned long long*)(wbase + d0 + 16) = ((unsigned long long)q3 << 32) | q2;
}

// ---------------------------------------------------------------------------
// Fused fp8 GEMM: rowsum[i] += sum_j exp( (Xn8[i]/16 . Nn8[j]/16) )
// Tile 256x128, 512 threads = 8 waves of 64x64 (wave grid 4 rows x 2 cols).
// BK=64-B permuted windows, TWO-stage LDS (24 KB/stage, 48 KB total),
// distance-1 prefetch with R6-proven ordering: barrier -> STAGE(s+1 into
// other buf) -> COMPUTE(s). Stage s+1 is in flight for a full compute phase
// (~1.2k cyc > HBM latency), so the barrier's vmcnt(0) drain is ~free.
// WAR-safe: buf (s+1)&1 was read in phase s-1, done before this barrier.
// Per phase per wave: 8 conflict-free ds_read_b128 + 32 MFMA.
// ---------------------------------------------------------------------------
__global__ __launch_bounds__(512, 4)
void gemm_exp_rowsum(const unsigned char* __restrict__ Xn,
                     const unsigned char* __restrict__ Nn,
                     float* __restrict__ rowsum) {
    constexpr int KB = DIM;          // 1024 bytes per fp8 row
    constexpr int BK = 64;           // bytes per stage-row (one permuted window)
    __shared__ __align__(16) unsigned char Ash[2][256 * BK];   // 2 x 16 KB
    __shared__ __align__(16) unsigned char Bsh[2][128 * BK];   // 2 x  8 KB

    const int tid  = threadIdx.x;
    const int lane = tid & 63;
    const int wave = tid >> 6;                 // 0..7
    const int rowBase = blockIdx.y * 256;
    const int colBase = blockIdx.x * 128;

    // staging: one glds = 1 KB = 16 rows x 64 B; lane -> (row, chunk)
    const int srow   = lane >> 2;                       // 0..15
    const int schunk = (lane & 3) ^ ((srow >> 1) & 3);  // global-side swizzle
    const unsigned char* gA0 = Xn + (size_t)(rowBase +       wave * 16 + srow) * KB + schunk * 16;
    const unsigned char* gA1 = Xn + (size_t)(rowBase + 128 + wave * 16 + srow) * KB + schunk * 16;
    const unsigned char* gB  = Nn + (size_t)(colBase +       wave * 16 + srow) * KB + schunk * 16;
    const int lgA0 = (wave * 16) * BK;
    const int lgA1 = (wave * 16 + 128) * BK;
    const int lgB  = (wave * 16) * BK;

    const f32x4 fz = {0.f, 0.f, 0.f, 0.f};
    f32x4 acc[4][4];
#pragma unroll
    for (int mi = 0; mi < 4; mi++)
#pragma unroll
        for (int ni = 0; ni < 4; ni++) acc[mi][ni] = fz;

    const int m0   = (wave >> 1) * 64;   // 0..192
    const int n0   = (wave & 1) * 64;    // 0,64
    const int quad = lane >> 4;
    const int mrow = lane & 15;
    const int kx   = (mrow >> 1) & 3;    // read-side swizzle key

    int aoff[4], boff[4];
#pragma unroll
    for (int i = 0; i < 4; i++) {
        aoff[i] = (m0 + i * 16 + mrow) * BK + ((quad ^ kx) << 4);
        boff[i] = (n0 + i * 16 + mrow) * BK + ((quad ^ kx) << 4);
    }

#define STAGE(buf, stg)                                                  \
    do {                                                                 \
        const int kq = (stg) * BK;                                       \
        async_copy16(gA0 + kq, &Ash[buf][lgA0]);                         \
        async_copy16(gA1 + kq, &Ash[buf][lgA1]);                         \
        async_copy16(gB  + kq, &Bsh[buf][lgB]);                          \
    } while (0)

#define COMPUTE(buf)                                                     \
    do {                                                                 \
        longx2 a2[4], b2[4];                                             \
        _Pragma("unroll")                                                \
        for (int i = 0; i < 4; i++) {                                    \
            a2[i] = *(const longx2*)&Ash[buf][aoff[i]];                  \
            b2[i] = *(const longx2*)&Bsh[buf][boff[i]];                  \
        }                                                                \
        _Pragma("unroll")                                                \
        for (int mi = 0; mi < 4; mi++)                                   \
            _Pragma("unroll")                                            \
            for (int ni = 0; ni < 4; ni++) {                             \
                acc[mi][ni] = __builtin_amdgcn_mfma_f32_16x16x32_fp8_fp8( \
                    a2[mi].x, b2[ni].x, acc[mi][ni], 0, 0, 0);           \
                acc[mi][ni] = __builtin_amdgcn_mfma_f32_16x16x32_fp8_fp8( \
                    a2[mi].y, b2[ni].y, acc[mi][ni], 0, 0, 0);           \
            }                                                            \
    } while (0)

    STAGE(0, 0);
    // 16 phases, phase s reads buf s&1; stage s+1 issued right after the
    // barrier at the top of phase s (distance-1, in flight a full phase).
#pragma unroll 1
    for (int it = 0; it < 8; it++) {
        __syncthreads();
        STAGE(1, 2 * it + 1);
        COMPUTE(0);
        __syncthreads();
        if (it < 7) STAGE(0, 2 * it + 2);
        COMPUTE(1);
    }
#undef STAGE
#undef COMPUTE

    // epilogue: undo x16*x16 scaling (1/256), exp, 16-col reduce, atomics.
    // C/D layout: col=lane&15, row=quad*4+reg.
#pragma unroll
    for (int mi = 0; mi < 4; mi++) {
        float rs0 = 0.f, rs1 = 0.f, rs2 = 0.f, rs3 = 0.f;
#pragma unroll
        for (int ni = 0; ni < 4; ni++) {
            rs0 += __expf(acc[mi][ni].x * 0.00390625f);
            rs1 += __expf(acc[mi][ni].y * 0.00390625f);
            rs2 += __expf(acc[mi][ni].z * 0.00390625f);
            rs3 += __expf(acc[mi][ni].w * 0.00390625f);
        }
#pragma unroll
        for (int off = 1; off < 16; off <<= 1) {
            rs0 += __shfl_xor(rs0, off);
            rs1 += __shfl_xor(rs1, off);
            rs2 += __shfl_xor(rs2, off);
            rs3 += __shfl_xor(rs3, off);
        }
        if ((lane & 15) == 0) {
            const int r = rowBase + m0 + mi * 16 + quad * 4;
            atomicAdd(&rowsum[r + 0], rs0);
            atomicAdd(&rowsum[r + 1], rs1);
            atomicAdd(&rowsum[r + 2], rs2);
            atomicAdd(&rowsum[r + 3], rs3);
        }
    }
}

__global__ __launch_bounds__(1024)
void loss_kernel(const float* __restrict__ rowsum, const float* __restrict__ sim,
                 float* __restrict__ out, int bn) {
    const int tid  = threadIdx.x;
    const int lane = tid & 63;
    const int wave = tid >> 6;
    float acc = 0.f;
    for (int i = tid; i < bn; i += 1024) acc += logf(rowsum[i]) - sim[i];
#pragma unroll
    for (int off = 1; off < 64; off <<= 1) acc += __shfl_xor(acc, off);
    __shared__ float red[16];
    if (lane == 0) red[wave] = acc;
    __syncthreads();
    if (tid == 0) {
        float t = 0.f;
#pragma unroll
        for (int i = 0; i < 16; i++) t += red[i];
        out[0] = t / (float)bn;
    }
}

extern "C" void kernel_launch(void* const* d_in, const int* in_sizes, int n_in,
                              void* d_out, int out_size, void* d_ws, size_t ws_size,
                              hipStream_t stream) {
    const float* x   = (const float*)d_in[0];
    const float* pos = (const float*)d_in[1];
    const float* neg = (const float*)d_in[2];
    const int bn = in_sizes[0] / DIM;  // 4096
    const int cn = in_sizes[2] / DIM;  // 8192

    // ws layout: Xn fp8 [bn*DIM] | Nn fp8 [cn*DIM] | sim f32 [bn] | rowsum f32 [bn]
    unsigned char* Xn = (unsigned char*)d_ws;
    unsigned char* Nn = Xn + (size_t)bn * DIM;
    float* sim    = (float*)(Nn + (size_t)cn * DIM);
    float* rowsum = sim + bn;

    prep_all<<<dim3((bn + cn) / 4), dim3(256), 0, stream>>>(
        x, pos, neg, Xn, Nn, sim, rowsum, bn);
    gemm_exp_rowsum<<<dim3(cn / 128, bn / 256), dim3(512), 0, stream>>>(Xn, Nn, rowsum);
    loss_kernel<<<dim3(1), dim3(1024), 0, stream>>>(rowsum, sim, (float*)d_out, bn);
}